// Round 2
// baseline (2170.028 us; speedup 1.0000x reference)
//
#include <hip/hip_runtime.h>

// InteractionBlock (MACE-style) on MI355X.
// Float dtype (bf16 vs fp32) is AMBIGUOUS from the harness -> detected at
// runtime by k_detect (decodes node_feats as bf16; fp32-reinterpreted data
// shows wild exponents). Flag stored in ws; all kernels branch uniformly.
//
// Pipeline:
//   k_detect   : dtype flag -> ws
//   memset     : zero msg_s/msg_v accumulators
//   k_prep     : convert+scale all weights ->fp32 into ws ("cw" table)
//   k_node_up  : s_up = s@Wup0/8, v_up = v@Wup1/8      (per-node, lane=channel)
//   k_edge     : edge MLP (8->64->64->64->320) + message assembly + atomic scatter
//   k_node_out : msg@Wl0/Wl1, species polynomial, @Wp0/Wp1, store out
//
// ws layout (floats), nN=20000:
//   sup   [nN*64 ]  @ 0
//   vup   [nN*192]  @ nN*64
//   msg_s [nN*128]  @ nN*256
//   msg_v [nN*576]  @ nN*384
//   cw    [71808 ]  @ nN*960
//   flag  [1     ]  @ nN*960 + 71808     total ~77.1 MB

typedef unsigned short u16;
typedef unsigned int u32;

#define CW_UP0 0
#define CW_UP1 4096
#define CW_M1  8192
#define CW_M2  8704
#define CW_M3  12800
#define CW_M4  16896
#define CW_L0  37376
#define CW_L1  45568
#define CW_P0  57856
#define CW_P1  61952
#define CW_S01 66048
#define CW_S02 66688
#define CW_S03 67968
#define CW_S11 69248
#define CW_S12 69888
#define CW_S13 70528
#define CW_TOTAL 71808

// E[silu(z)^2] over N(0,1) = 0.3557792 -> 1/sqrt = 1.6765224 (quadrature)
#define C_SILU     1.6765224f
#define INV_SQRT3  0.57735027f
#define INV_SQRT2  0.70710678f

__device__ __forceinline__ float b2f(u16 u) {
  union { u32 i; float f; } x; x.i = ((u32)u) << 16; return x.f;
}
__device__ __forceinline__ u16 f2b(float f) {
  union { float f; u32 i; } x; x.f = f;
  u32 i = x.i;
  u32 r = (i + 0x7fffu + ((i >> 16) & 1u)) >> 16;
  return (u16)r;
}
// dual-dtype load: element index i of a bf16 (u16) or fp32 array
__device__ __forceinline__ float ldf(const void* p, size_t i, int f32) {
  return f32 ? ((const float*)p)[i] : b2f(((const u16*)p)[i]);
}
__device__ __forceinline__ float silu_n(float x) {
  return C_SILU * x / (1.0f + __expf(-x));
}

// ---- dtype detector: bf16 N(0,1) data has sane exponents; fp32 bytes
// reinterpreted as bf16 give ~37% wild magnitudes.
__global__ void k_detect(const void* nf, int* flag) {
  __shared__ int cnt;
  if (threadIdx.x == 0) cnt = 0;
  __syncthreads();
  const u16* p = (const u16*)nf;
  int wild = 0;
  for (int i = threadIdx.x; i < 4096; i += 256) {
    float ax = fabsf(b2f(p[i]));
    if (!(ax <= 1e10f) || (ax != 0.f && ax < 1e-10f)) wild++;
  }
  atomicAdd(&cnt, wild);
  __syncthreads();
  if (threadIdx.x == 0) *flag = (cnt > 100) ? 1 : 0;
}

struct WPtrs { const void* p[16]; };

__global__ __launch_bounds__(256) void k_prep(WPtrs wp, float* __restrict__ cw,
                                              const int* __restrict__ flagp) {
  const int   sizes[16]  = {4096,4096,512,4096,4096,20480,8192,12288,4096,4096,
                            640,1280,1280,640,640,1280};
  const float scales[16] = {0.125f,0.125f,0.35355339f,0.125f,0.125f,0.125f,
                            0.08838835f,0.07216878f,0.125f,0.125f,
                            1.f,1.f,1.f,1.f,1.f,1.f};
  const int f32 = *flagp;
  int gid = blockIdx.x * 256 + threadIdx.x;
  if (gid >= CW_TOTAL) return;
  int off = gid, seg = 0;
  while (off >= sizes[seg]) { off -= sizes[seg]; seg++; }
  cw[gid] = ldf(wp.p[seg], off, f32) * scales[seg];
}

// ---- node up-projection: 4 nodes per block (one wave each), lane = out channel
__global__ __launch_bounds__(256) void k_node_up(
    const void* __restrict__ nf, const float* __restrict__ cw,
    float* __restrict__ sup, float* __restrict__ vup, int nN,
    const int* __restrict__ flagp) {
  __shared__ float row[4][256];
  const int f32 = *flagp;
  int w = threadIdx.x >> 6, l = threadIdx.x & 63;
  int n = blockIdx.x * 4 + w;
  bool valid = n < nN;
  int nn = valid ? n : 0;
#pragma unroll
  for (int t = 0; t < 4; t++)
    row[w][t * 64 + l] = ldf(nf, (size_t)nn * 256 + t * 64 + l, f32);
  __syncthreads();
  float sacc = 0.f, v0 = 0.f, v1 = 0.f, v2 = 0.f;
#pragma unroll 8
  for (int c = 0; c < 64; c++) {
    float w0 = cw[CW_UP0 + c * 64 + l];
    float w1 = cw[CW_UP1 + c * 64 + l];
    sacc += row[w][c] * w0;
    v0 += row[w][64 + c * 3 + 0] * w1;
    v1 += row[w][64 + c * 3 + 1] * w1;
    v2 += row[w][64 + c * 3 + 2] * w1;
  }
  if (valid) {
    sup[(size_t)n * 64 + l] = sacc;
    vup[(size_t)n * 192 + l * 3 + 0] = v0;
    vup[(size_t)n * 192 + l * 3 + 1] = v1;
    vup[(size_t)n * 192 + l * 3 + 2] = v2;
  }
}

// ---- edge kernel: 4 waves/block, each wave handles 4 edges, lane = channel
__global__ __launch_bounds__(256) void k_edge(
    const void* __restrict__ ef, const void* __restrict__ ea,
    const int* __restrict__ ie, const int* __restrict__ je,
    const float* __restrict__ cw, const float* __restrict__ sup,
    const float* __restrict__ vup, float* __restrict__ msg_s,
    float* __restrict__ msg_v, int nE, const int* __restrict__ flagp) {
  __shared__ float hl[4][256];  // [wave][k*4+e]
  const int f32 = *flagp;
  int w = threadIdx.x >> 6, l = threadIdx.x & 63;
  int e0 = blockIdx.x * 16 + w * 4;

  // layer 1: 8 -> 64
  float h[4];
#pragma unroll
  for (int e = 0; e < 4; e++) {
    int ee = min(e0 + e, nE - 1);
    float acc = 0.f;
#pragma unroll
    for (int b = 0; b < 8; b++)
      acc += ldf(ef, (size_t)ee * 8 + b, f32) * cw[CW_M1 + b * 64 + l];
    h[e] = silu_n(acc);
  }
  *(float4*)&hl[w][l * 4] = make_float4(h[0], h[1], h[2], h[3]);
  __syncthreads();

  // layer 2: 64 -> 64
  float a0 = 0.f, a1 = 0.f, a2 = 0.f, a3 = 0.f;
#pragma unroll 8
  for (int k = 0; k < 64; k++) {
    float4 hk = *(const float4*)&hl[w][k * 4];
    float wk = cw[CW_M2 + k * 64 + l];
    a0 += hk.x * wk; a1 += hk.y * wk; a2 += hk.z * wk; a3 += hk.w * wk;
  }
  __syncthreads();
  h[0] = silu_n(a0); h[1] = silu_n(a1); h[2] = silu_n(a2); h[3] = silu_n(a3);
  *(float4*)&hl[w][l * 4] = make_float4(h[0], h[1], h[2], h[3]);
  __syncthreads();

  // layer 3: 64 -> 64
  a0 = a1 = a2 = a3 = 0.f;
#pragma unroll 8
  for (int k = 0; k < 64; k++) {
    float4 hk = *(const float4*)&hl[w][k * 4];
    float wk = cw[CW_M3 + k * 64 + l];
    a0 += hk.x * wk; a1 += hk.y * wk; a2 += hk.z * wk; a3 += hk.w * wk;
  }
  __syncthreads();
  h[0] = silu_n(a0); h[1] = silu_n(a1); h[2] = silu_n(a2); h[3] = silu_n(a3);
  *(float4*)&hl[w][l * 4] = make_float4(h[0], h[1], h[2], h[3]);
  __syncthreads();

  // layer 4: 64 -> 320 (5 blocks of 64: wa wb wc wd we), per edge
  float t[5][4];
#pragma unroll
  for (int p = 0; p < 5; p++)
#pragma unroll
    for (int e = 0; e < 4; e++) t[p][e] = 0.f;
#pragma unroll 4
  for (int k = 0; k < 64; k++) {
    float4 hk = *(const float4*)&hl[w][k * 4];
    const float* wb = &cw[CW_M4 + k * 320 + l];
#pragma unroll
    for (int p = 0; p < 5; p++) {
      float wk = wb[p * 64];
      t[p][0] += hk.x * wk; t[p][1] += hk.y * wk;
      t[p][2] += hk.z * wk; t[p][3] += hk.w * wk;
    }
  }

  // messages + scatter
#pragma unroll
  for (int e = 0; e < 4; e++) {
    int ee = e0 + e;
    bool valid = ee < nE;
    int ec = valid ? ee : 0;
    float eas = ldf(ea, (size_t)ec * 4 + 0, f32);
    float ev0 = ldf(ea, (size_t)ec * 4 + 1, f32);
    float ev1 = ldf(ea, (size_t)ec * 4 + 2, f32);
    float ev2 = ldf(ea, (size_t)ec * 4 + 3, f32);
    int i = ie[ec], j = je[ec];
    float xs  = sup[(size_t)i * 64 + l];
    float xv0 = vup[(size_t)i * 192 + l * 3 + 0];
    float xv1 = vup[(size_t)i * 192 + l * 3 + 1];
    float xv2 = vup[(size_t)i * 192 + l * 3 + 2];
    float wa = t[0][e], wbv = t[1][e], wc = t[2][e], wd = t[3][e], we_ = t[4][e];
    float dot = xv0 * ev0 + xv1 * ev1 + xv2 * ev2;
    float m0 = wa * xs * eas;
    float m1 = wbv * dot * INV_SQRT3;
    float c0 = xv1 * ev2 - xv2 * ev1;
    float c1 = xv2 * ev0 - xv0 * ev2;
    float c2 = xv0 * ev1 - xv1 * ev0;
    float wcxs = wc * xs, wde = wd * eas, wef = we_ * INV_SQRT2;
    if (valid) {
      float* ms = msg_s + (size_t)j * 128;
      atomicAdd(ms + l, m0);
      atomicAdd(ms + 64 + l, m1);
      float* mv = msg_v + (size_t)j * 576;
      atomicAdd(mv + l * 3 + 0, wcxs * ev0);
      atomicAdd(mv + l * 3 + 1, wcxs * ev1);
      atomicAdd(mv + l * 3 + 2, wcxs * ev2);
      atomicAdd(mv + 192 + l * 3 + 0, wde * xv0);
      atomicAdd(mv + 192 + l * 3 + 1, wde * xv1);
      atomicAdd(mv + 192 + l * 3 + 2, wde * xv2);
      atomicAdd(mv + 384 + l * 3 + 0, wef * c0);
      atomicAdd(mv + 384 + l * 3 + 1, wef * c1);
      atomicAdd(mv + 384 + l * 3 + 2, wef * c2);
    }
  }
}

// ---- node output: 4 nodes per block (one wave each), lane = out channel
__global__ __launch_bounds__(256) void k_node_out(
    const float* __restrict__ msg_s, const float* __restrict__ msg_v,
    const int* __restrict__ an, const float* __restrict__ cw,
    void* __restrict__ out, int nN, const int* __restrict__ flagp) {
  // per-wave buffer: ms[0:128] mv[128:704] os[704:768] ov[768:960]
  __shared__ float buf[4][960];
  const int f32 = *flagp;
  int w = threadIdx.x >> 6, l = threadIdx.x & 63;
  int n = blockIdx.x * 4 + w;
  bool valid = n < nN;
  int nn = valid ? n : 0;
  float* B = buf[w];
  const float* ms_g = msg_s + (size_t)nn * 128;
  const float* mv_g = msg_v + (size_t)nn * 576;
  B[l] = ms_g[l];
  B[64 + l] = ms_g[64 + l];
#pragma unroll
  for (int t = 0; t < 9; t++) B[128 + t * 64 + l] = mv_g[t * 64 + l];
  __syncthreads();

  float s2 = 0.f;
#pragma unroll 8
  for (int c = 0; c < 128; c++) s2 += B[c] * cw[CW_L0 + c * 64 + l];
  float v20 = 0.f, v21 = 0.f, v22 = 0.f;
#pragma unroll 8
  for (int c = 0; c < 192; c++) {
    float wk = cw[CW_L1 + c * 64 + l];
    v20 += B[128 + c * 3 + 0] * wk;
    v21 += B[128 + c * 3 + 1] * wk;
    v22 += B[128 + c * 3 + 2] * wk;
  }
  int a = an[nn];
  float w01  = cw[CW_S01 + a * 64 + l];
  float w02a = cw[CW_S02 + a * 128 + l];
  float w02b = cw[CW_S02 + a * 128 + 64 + l];
  float w03a = cw[CW_S03 + a * 128 + l];
  float w03b = cw[CW_S03 + a * 128 + 64 + l];
  float w11  = cw[CW_S11 + a * 64 + l];
  float w12  = cw[CW_S12 + a * 64 + l];
  float w13a = cw[CW_S13 + a * 128 + l];
  float w13b = cw[CW_S13 + a * 128 + 64 + l];

  float vv = v20 * v20 + v21 * v21 + v22 * v22;
  float s2sq = s2 * s2;
  float vvs = vv * INV_SQRT3;
  float outs = w01 * s2 + w02a * s2sq + w02b * vvs + w03a * s2sq * s2 +
               w03b * s2 * vvs;
  float coef = w11 + w12 * s2 + w13a * s2sq + w13b * vvs;

  B[704 + l] = outs;
  B[768 + l * 3 + 0] = coef * v20;
  B[768 + l * 3 + 1] = coef * v21;
  B[768 + l * 3 + 2] = coef * v22;
  __syncthreads();

  float so = 0.f, vo0 = 0.f, vo1 = 0.f, vo2 = 0.f;
#pragma unroll 8
  for (int c = 0; c < 64; c++) {
    float w0 = cw[CW_P0 + c * 64 + l];
    float w1 = cw[CW_P1 + c * 64 + l];
    so  += B[704 + c] * w0;
    vo0 += B[768 + c * 3 + 0] * w1;
    vo1 += B[768 + c * 3 + 1] * w1;
    vo2 += B[768 + c * 3 + 2] * w1;
  }
  if (valid) {
    size_t base = (size_t)n * 256;
    if (f32) {
      float* o = (float*)out;
      o[base + l] = so;
      o[base + 64 + l * 3 + 0] = vo0;
      o[base + 64 + l * 3 + 1] = vo1;
      o[base + 64 + l * 3 + 2] = vo2;
    } else {
      u16* o = (u16*)out;
      o[base + l] = f2b(so);
      o[base + 64 + l * 3 + 0] = f2b(vo0);
      o[base + 64 + l * 3 + 1] = f2b(vo1);
      o[base + 64 + l * 3 + 2] = f2b(vo2);
    }
  }
}

extern "C" void kernel_launch(void* const* d_in, const int* in_sizes, int n_in,
                              void* d_out, int out_size, void* d_ws,
                              size_t ws_size, hipStream_t stream) {
  const void* nf = d_in[0];
  const void* ef = d_in[1];
  const void* ea = d_in[2];
  const int* ie = (const int*)d_in[3];
  const int* je = (const int*)d_in[4];
  const int* an = (const int*)d_in[5];
  int nN = in_sizes[0] / 256;   // 20000
  int nE = in_sizes[3];         // 320000

  float* ws    = (float*)d_ws;
  float* sup   = ws;
  float* vup   = sup + (size_t)nN * 64;
  float* msg_s = vup + (size_t)nN * 192;
  float* msg_v = msg_s + (size_t)nN * 128;
  float* cw    = msg_v + (size_t)nN * 576;
  int*   flag  = (int*)(cw + CW_TOTAL);

  k_detect<<<1, 256, 0, stream>>>(nf, flag);

  // zero message accumulators
  hipMemsetAsync(msg_s, 0, (size_t)nN * 704 * sizeof(float), stream);

  WPtrs wp;
  const int widx[16] = {6, 7, 8, 9, 10, 11, 12, 13, 20, 21,
                        14, 15, 16, 17, 18, 19};
  for (int i = 0; i < 16; i++) wp.p[i] = d_in[widx[i]];
  k_prep<<<(CW_TOTAL + 255) / 256, 256, 0, stream>>>(wp, cw, flag);

  k_node_up<<<(nN + 3) / 4, 256, 0, stream>>>(nf, cw, sup, vup, nN, flag);
  k_edge<<<(nE + 15) / 16, 256, 0, stream>>>(ef, ea, ie, je, cw, sup, vup,
                                             msg_s, msg_v, nE, flag);
  k_node_out<<<(nN + 3) / 4, 256, 0, stream>>>(msg_s, msg_v, an, cw, d_out,
                                               nN, flag);
}

// Round 3
// 872.761 us; speedup vs baseline: 2.4864x; 2.4864x over previous
//
#include <hip/hip_runtime.h>

// InteractionBlock (MACE-style) on MI355X — round 3: atomic-free.
// R2 post-mortem: k_edge 1949us, WRITE_SIZE 2.32GB = fp32 atomic scatter
// write-through; VALUBusy 10.5%. Fix: CSR over jedges + one-wave-per-node
// fused gather (MLP + messages + node-out in registers/LDS, no atomics).
//
// Pipeline:
//   k_detect  : bf16-vs-fp32 flag -> ws (uniform branch everywhere)
//   memset    : zero deg[]
//   k_prep    : convert+scale all weights ->fp32 "cw" table
//   k_hist    : deg[j]++ per edge
//   k_scan    : exclusive prefix sum (single block) -> offs, cursor
//   k_scatter : eidx[cursor[j]++] = e   (CSR edge ids per dest node)
//   k_node_up : sup = s@Wup0/8 (fp32), vup planar (fp32)
//   k_gather  : per node-wave: edge MLP (4-edge chunks, LDS h) + messages
//               (11 acc regs) + Wl0/Wl1 + species poly + Wp0/Wp1 + store
//
// ws (ints then floats, ~22.3 MB):
//   deg[nN] offs[nN+1] cursor[nN] eidx[nE] | cw[71808] sup[nN*64]
//   vup[nN*192 planar (n*3+m)*64+l] | flag

typedef unsigned short u16;
typedef unsigned int u32;

#define CW_UP0 0
#define CW_UP1 4096
#define CW_M1  8192
#define CW_M2  8704
#define CW_M3  12800
#define CW_M4  16896
#define CW_L0  37376
#define CW_L1  45568
#define CW_P0  57856
#define CW_P1  61952
#define CW_S01 66048
#define CW_S02 66688
#define CW_S03 67968
#define CW_S11 69248
#define CW_S12 69888
#define CW_S13 70528
#define CW_TOTAL 71808

#define C_SILU     1.6765224f
#define INV_SQRT3  0.57735027f
#define INV_SQRT2  0.70710678f

__device__ __forceinline__ float b2f(u16 u) {
  union { u32 i; float f; } x; x.i = ((u32)u) << 16; return x.f;
}
__device__ __forceinline__ u16 f2b(float f) {
  union { float f; u32 i; } x; x.f = f;
  u32 i = x.i;
  u32 r = (i + 0x7fffu + ((i >> 16) & 1u)) >> 16;
  return (u16)r;
}
__device__ __forceinline__ float ldf(const void* p, size_t i, int f32) {
  return f32 ? ((const float*)p)[i] : b2f(((const u16*)p)[i]);
}
__device__ __forceinline__ float silu_n(float x) {
  return C_SILU * x / (1.0f + __expf(-x));
}

// ---- dtype detector
__global__ void k_detect(const void* nf, int* flag) {
  __shared__ int cnt;
  if (threadIdx.x == 0) cnt = 0;
  __syncthreads();
  const u16* p = (const u16*)nf;
  int wild = 0;
  for (int i = threadIdx.x; i < 4096; i += 256) {
    float ax = fabsf(b2f(p[i]));
    if (!(ax <= 1e10f) || (ax != 0.f && ax < 1e-10f)) wild++;
  }
  atomicAdd(&cnt, wild);
  __syncthreads();
  if (threadIdx.x == 0) *flag = (cnt > 100) ? 1 : 0;
}

struct WPtrs { const void* p[16]; };

__global__ __launch_bounds__(256) void k_prep(WPtrs wp, float* __restrict__ cw,
                                              const int* __restrict__ flagp) {
  const int   sizes[16]  = {4096,4096,512,4096,4096,20480,8192,12288,4096,4096,
                            640,1280,1280,640,640,1280};
  const float scales[16] = {0.125f,0.125f,0.35355339f,0.125f,0.125f,0.125f,
                            0.08838835f,0.07216878f,0.125f,0.125f,
                            1.f,1.f,1.f,1.f,1.f,1.f};
  const int f32 = *flagp;
  int gid = blockIdx.x * 256 + threadIdx.x;
  if (gid >= CW_TOTAL) return;
  int off = gid, seg = 0;
  while (off >= sizes[seg]) { off -= sizes[seg]; seg++; }
  cw[gid] = ldf(wp.p[seg], off, f32) * scales[seg];
}

// ---- CSR build
__global__ __launch_bounds__(256) void k_hist(const int* __restrict__ je,
                                              int* __restrict__ deg, int nE) {
  int e = blockIdx.x * 256 + threadIdx.x;
  if (e < nE) atomicAdd(&deg[je[e]], 1);
}

__global__ __launch_bounds__(256) void k_scan(const int* __restrict__ deg,
                                              int* __restrict__ offs,
                                              int* __restrict__ cursor, int nN) {
  __shared__ int part[256];
  int t = threadIdx.x;
  int per = (nN + 255) / 256;
  int lo = t * per, hi = (t + 1) * per; if (hi > nN) hi = nN;
  int s = 0;
  for (int i = lo; i < hi; i++) s += deg[i];
  part[t] = s;
  __syncthreads();
  if (t == 0) {
    int run = 0;
    for (int i = 0; i < 256; i++) { int v = part[i]; part[i] = run; run += v; }
    offs[nN] = run;
  }
  __syncthreads();
  int run = part[t];
  for (int i = lo; i < hi; i++) {
    offs[i] = run; cursor[i] = run; run += deg[i];
  }
}

__global__ __launch_bounds__(256) void k_scatter(const int* __restrict__ je,
                                                 int* __restrict__ cursor,
                                                 int* __restrict__ eidx, int nE) {
  int e = blockIdx.x * 256 + threadIdx.x;
  if (e < nE) {
    int pos = atomicAdd(&cursor[je[e]], 1);
    eidx[pos] = e;
  }
}

// ---- node up-projection: sup fp32, vup fp32 planar [(n*3+m)*64+l]
__global__ __launch_bounds__(256) void k_node_up(
    const void* __restrict__ nf, const float* __restrict__ cw,
    float* __restrict__ sup, float* __restrict__ vup, int nN,
    const int* __restrict__ flagp) {
  __shared__ float row[4][256];
  const int f32 = *flagp;
  int w = threadIdx.x >> 6, l = threadIdx.x & 63;
  int n = blockIdx.x * 4 + w;
  bool valid = n < nN;
  int nn = valid ? n : 0;
#pragma unroll
  for (int t = 0; t < 4; t++)
    row[w][t * 64 + l] = ldf(nf, (size_t)nn * 256 + t * 64 + l, f32);
  __syncthreads();
  float sacc = 0.f, v0 = 0.f, v1 = 0.f, v2 = 0.f;
#pragma unroll 8
  for (int c = 0; c < 64; c++) {
    float w0 = cw[CW_UP0 + c * 64 + l];
    float w1 = cw[CW_UP1 + c * 64 + l];
    sacc += row[w][c] * w0;
    v0 += row[w][64 + c * 3 + 0] * w1;
    v1 += row[w][64 + c * 3 + 1] * w1;
    v2 += row[w][64 + c * 3 + 2] * w1;
  }
  if (valid) {
    sup[(size_t)n * 64 + l] = sacc;
    vup[((size_t)n * 3 + 0) * 64 + l] = v0;
    vup[((size_t)n * 3 + 1) * 64 + l] = v1;
    vup[((size_t)n * 3 + 2) * 64 + l] = v2;
  }
}

// ---- fused gather: one wave per node, lane = channel
__global__ __launch_bounds__(256) void k_gather(
    const void* __restrict__ ef, const void* __restrict__ ea,
    const int* __restrict__ ie, const int* __restrict__ offs,
    const int* __restrict__ eidx, const float* __restrict__ sup,
    const float* __restrict__ vup, const int* __restrict__ an,
    const float* __restrict__ cw, void* __restrict__ out, int nN,
    const int* __restrict__ flagp) {
  __shared__ float hl[4][256];   // [wave][k*4+e]
  __shared__ float B[4][960];    // node-out staging
  __shared__ int mdeg;
  const int f32 = *flagp;
  int w = threadIdx.x >> 6, l = threadIdx.x & 63;
  int n = blockIdx.x * 4 + w;
  int nn = (n < nN) ? n : 0;
  int start = offs[nn];
  int deg = offs[nn + 1] - start;

  if (threadIdx.x == 0) mdeg = 0;
  __syncthreads();
  if (l == 0) atomicMax(&mdeg, deg);
  __syncthreads();
  int iters = (mdeg + 3) / 4;    // block-uniform

  float as0 = 0.f, as1 = 0.f;
  float av[9];
#pragma unroll
  for (int q = 0; q < 9; q++) av[q] = 0.f;

  for (int it = 0; it < iters; it++) {
    int c0 = it * 4;
    int cnt = deg - c0;
    if (cnt < 0) cnt = 0;
    if (cnt > 4) cnt = 4;
    int eid[4];
#pragma unroll
    for (int e = 0; e < 4; e++)
      eid[e] = (c0 + e < deg) ? eidx[start + c0 + e] : 0;

    // layer 1: 8 -> 64
    float h[4];
#pragma unroll
    for (int e = 0; e < 4; e++) {
      float ev[8];
      if (f32) {
        const float4* p = (const float4*)ef;
        float4 q0 = p[(size_t)eid[e] * 2];
        float4 q1 = p[(size_t)eid[e] * 2 + 1];
        ev[0]=q0.x; ev[1]=q0.y; ev[2]=q0.z; ev[3]=q0.w;
        ev[4]=q1.x; ev[5]=q1.y; ev[6]=q1.z; ev[7]=q1.w;
      } else {
        const uint4* p = (const uint4*)ef;
        uint4 q = p[eid[e]];
        ev[0]=b2f(q.x & 0xffff); ev[1]=b2f(q.x >> 16);
        ev[2]=b2f(q.y & 0xffff); ev[3]=b2f(q.y >> 16);
        ev[4]=b2f(q.z & 0xffff); ev[5]=b2f(q.z >> 16);
        ev[6]=b2f(q.w & 0xffff); ev[7]=b2f(q.w >> 16);
      }
      float acc = 0.f;
#pragma unroll
      for (int b = 0; b < 8; b++) acc += ev[b] * cw[CW_M1 + b * 64 + l];
      h[e] = silu_n(acc);
    }
    *(float4*)&hl[w][l * 4] = make_float4(h[0], h[1], h[2], h[3]);
    __syncthreads();

    // layer 2: 64 -> 64
    float a0 = 0.f, a1 = 0.f, a2 = 0.f, a3 = 0.f;
#pragma unroll 8
    for (int k = 0; k < 64; k++) {
      float4 hk = *(const float4*)&hl[w][k * 4];
      float wk = cw[CW_M2 + k * 64 + l];
      a0 += hk.x * wk; a1 += hk.y * wk; a2 += hk.z * wk; a3 += hk.w * wk;
    }
    __syncthreads();
    h[0] = silu_n(a0); h[1] = silu_n(a1); h[2] = silu_n(a2); h[3] = silu_n(a3);
    *(float4*)&hl[w][l * 4] = make_float4(h[0], h[1], h[2], h[3]);
    __syncthreads();

    // layer 3: 64 -> 64
    a0 = a1 = a2 = a3 = 0.f;
#pragma unroll 8
    for (int k = 0; k < 64; k++) {
      float4 hk = *(const float4*)&hl[w][k * 4];
      float wk = cw[CW_M3 + k * 64 + l];
      a0 += hk.x * wk; a1 += hk.y * wk; a2 += hk.z * wk; a3 += hk.w * wk;
    }
    __syncthreads();
    h[0] = silu_n(a0); h[1] = silu_n(a1); h[2] = silu_n(a2); h[3] = silu_n(a3);
    *(float4*)&hl[w][l * 4] = make_float4(h[0], h[1], h[2], h[3]);
    __syncthreads();

    // layer 4: 64 -> 320
    float t[5][4];
#pragma unroll
    for (int p = 0; p < 5; p++)
#pragma unroll
      for (int e = 0; e < 4; e++) t[p][e] = 0.f;
#pragma unroll 4
    for (int k = 0; k < 64; k++) {
      float4 hk = *(const float4*)&hl[w][k * 4];
      const float* wb = &cw[CW_M4 + k * 320 + l];
#pragma unroll
      for (int p = 0; p < 5; p++) {
        float wk = wb[p * 64];
        t[p][0] += hk.x * wk; t[p][1] += hk.y * wk;
        t[p][2] += hk.z * wk; t[p][3] += hk.w * wk;
      }
    }

    // messages (wave-local, accumulate in registers)
    for (int e = 0; e < cnt; e++) {   // cnt is wave-uniform
      int ee = eid[e];
      float eas, ev0, ev1, ev2;
      if (f32) {
        const float4* p = (const float4*)ea;
        float4 q = p[ee];
        eas = q.x; ev0 = q.y; ev1 = q.z; ev2 = q.w;
      } else {
        const uint2* p = (const uint2*)ea;
        uint2 q = p[ee];
        eas = b2f(q.x & 0xffff); ev0 = b2f(q.x >> 16);
        ev1 = b2f(q.y & 0xffff); ev2 = b2f(q.y >> 16);
      }
      int i = ie[ee];
      float xs  = sup[(size_t)i * 64 + l];
      float xv0 = vup[((size_t)i * 3 + 0) * 64 + l];
      float xv1 = vup[((size_t)i * 3 + 1) * 64 + l];
      float xv2 = vup[((size_t)i * 3 + 2) * 64 + l];
      float dot = xv0 * ev0 + xv1 * ev1 + xv2 * ev2;
      as0 += t[0][e] * xs * eas;
      as1 += t[1][e] * dot * INV_SQRT3;
      float wcxs = t[2][e] * xs;
      float wde  = t[3][e] * eas;
      float wef  = t[4][e] * INV_SQRT2;
      av[0] += wcxs * ev0; av[1] += wcxs * ev1; av[2] += wcxs * ev2;
      av[3] += wde * xv0;  av[4] += wde * xv1;  av[5] += wde * xv2;
      av[6] += wef * (xv1 * ev2 - xv2 * ev1);
      av[7] += wef * (xv2 * ev0 - xv0 * ev2);
      av[8] += wef * (xv0 * ev1 - xv1 * ev0);
    }
    __syncthreads();
  }

  // ---- node-out (was k_node_out), msg from registers
  float* Bb = B[w];
  Bb[l] = as0;
  Bb[64 + l] = as1;
#pragma unroll
  for (int m = 0; m < 3; m++) {
    Bb[128 + l * 3 + m] = av[m];
    Bb[320 + l * 3 + m] = av[3 + m];
    Bb[512 + l * 3 + m] = av[6 + m];
  }
  __syncthreads();

  float s2 = 0.f;
#pragma unroll 8
  for (int c = 0; c < 128; c++) s2 += Bb[c] * cw[CW_L0 + c * 64 + l];
  float v20 = 0.f, v21 = 0.f, v22 = 0.f;
#pragma unroll 8
  for (int c = 0; c < 192; c++) {
    float wk = cw[CW_L1 + c * 64 + l];
    v20 += Bb[128 + c * 3 + 0] * wk;
    v21 += Bb[128 + c * 3 + 1] * wk;
    v22 += Bb[128 + c * 3 + 2] * wk;
  }
  int a = an[nn];
  float w01  = cw[CW_S01 + a * 64 + l];
  float w02a = cw[CW_S02 + a * 128 + l];
  float w02b = cw[CW_S02 + a * 128 + 64 + l];
  float w03a = cw[CW_S03 + a * 128 + l];
  float w03b = cw[CW_S03 + a * 128 + 64 + l];
  float w11  = cw[CW_S11 + a * 64 + l];
  float w12  = cw[CW_S12 + a * 64 + l];
  float w13a = cw[CW_S13 + a * 128 + l];
  float w13b = cw[CW_S13 + a * 128 + 64 + l];

  float vv = v20 * v20 + v21 * v21 + v22 * v22;
  float s2sq = s2 * s2;
  float vvs = vv * INV_SQRT3;
  float outs = w01 * s2 + w02a * s2sq + w02b * vvs + w03a * s2sq * s2 +
               w03b * s2 * vvs;
  float coef = w11 + w12 * s2 + w13a * s2sq + w13b * vvs;

  __syncthreads();
  Bb[704 + l] = outs;
  Bb[768 + l * 3 + 0] = coef * v20;
  Bb[768 + l * 3 + 1] = coef * v21;
  Bb[768 + l * 3 + 2] = coef * v22;
  __syncthreads();

  float so = 0.f, vo0 = 0.f, vo1 = 0.f, vo2 = 0.f;
#pragma unroll 8
  for (int c = 0; c < 64; c++) {
    float w0 = cw[CW_P0 + c * 64 + l];
    float w1 = cw[CW_P1 + c * 64 + l];
    so  += Bb[704 + c] * w0;
    vo0 += Bb[768 + c * 3 + 0] * w1;
    vo1 += Bb[768 + c * 3 + 1] * w1;
    vo2 += Bb[768 + c * 3 + 2] * w1;
  }
  if (n < nN) {
    size_t base = (size_t)n * 256;
    if (f32) {
      float* o = (float*)out;
      o[base + l] = so;
      o[base + 64 + l * 3 + 0] = vo0;
      o[base + 64 + l * 3 + 1] = vo1;
      o[base + 64 + l * 3 + 2] = vo2;
    } else {
      u16* o = (u16*)out;
      o[base + l] = f2b(so);
      o[base + 64 + l * 3 + 0] = f2b(vo0);
      o[base + 64 + l * 3 + 1] = f2b(vo1);
      o[base + 64 + l * 3 + 2] = f2b(vo2);
    }
  }
}

extern "C" void kernel_launch(void* const* d_in, const int* in_sizes, int n_in,
                              void* d_out, int out_size, void* d_ws,
                              size_t ws_size, hipStream_t stream) {
  const void* nf = d_in[0];
  const void* ef = d_in[1];
  const void* ea = d_in[2];
  const int* ie = (const int*)d_in[3];
  const int* je = (const int*)d_in[4];
  const int* an = (const int*)d_in[5];
  int nN = in_sizes[0] / 256;   // 20000
  int nE = in_sizes[3];         // 320000

  int* deg    = (int*)d_ws;
  int* offs   = deg + nN;            // nN+1
  int* cursor = offs + nN + 1;
  int* eidx   = cursor + nN;
  float* cw   = (float*)(eidx + nE);
  float* sup  = cw + CW_TOTAL;
  float* vup  = sup + (size_t)nN * 64;
  int* flag   = (int*)(vup + (size_t)nN * 192);

  k_detect<<<1, 256, 0, stream>>>(nf, flag);
  hipMemsetAsync(deg, 0, (size_t)nN * sizeof(int), stream);

  WPtrs wp;
  const int widx[16] = {6, 7, 8, 9, 10, 11, 12, 13, 20, 21,
                        14, 15, 16, 17, 18, 19};
  for (int i = 0; i < 16; i++) wp.p[i] = d_in[widx[i]];
  k_prep<<<(CW_TOTAL + 255) / 256, 256, 0, stream>>>(wp, cw, flag);

  k_hist<<<(nE + 255) / 256, 256, 0, stream>>>(je, deg, nE);
  k_scan<<<1, 256, 0, stream>>>(deg, offs, cursor, nN);
  k_scatter<<<(nE + 255) / 256, 256, 0, stream>>>(je, cursor, eidx, nE);

  k_node_up<<<(nN + 3) / 4, 256, 0, stream>>>(nf, cw, sup, vup, nN, flag);
  k_gather<<<(nN + 3) / 4, 256, 0, stream>>>(ef, ea, ie, offs, eidx, sup, vup,
                                             an, cw, d_out, nN, flag);
}